// Round 1
// baseline (298.479 us; speedup 1.0000x reference)
//
#include <hip/hip_runtime.h>
#include <hip/hip_bf16.h>

// MiniEq2Net fully-fused fp32 implementation.
// Sizes: B=8, n=256, nin=16, C=nhid=32, DH=128.
//
// Math (derived from reference):
//   h0 channels: e<16: (i==j)*x[i,e] ; e>=16: x[i,d]*x[j,d] (d=e-16). Symmetric!
//   h1[c,i,j] = relu( Q[c,i,j] + R1[c,i] + T1[c] + (i==j)*Dg1[c,i] )
//     Q[c,i,j]  = sum_d x[i,d] x[j,d] * (W1[16+d,c,0]+W1[16+d,c,1])   (rank-16, symmetric)
//     Dg1[c,i]  = sum_d x[i,d]*(W1[d,c,0]+W1[d,c,1]+W1[d,c,2]) + x[i,d]^2*W1[16+d,c,2]
//     R1[c,i]   = (1/n) sum_d x[i,d]*W1[d,c,3] + x[i,d]*S[d]*W1[16+d,c,3]
//     T1[c]     = (1/n^2) sum_d S[d]*W1[d,c,4] + S[d]^2*W1[16+d,c,4]  + b1[c]
//   out2[s,i,j] = sum_c h1[c,i,j]*W2[c,s,0] + h1[c,j,i]*W2[c,s,1]
//               + (i==j)*CD2[s,i] + CR2[s,i] + CT2[s]
//   g[b,s] = sum_ij relu(out2); then tiny MLP 32->128->128->1.
//
// h1 is NEVER materialized: Q is recomputed (512 FMA/elem) wherever needed;
// Q is shared between (i,j) and (j,i) so tile-pair blocks get the transpose free.

#define NB 8
#define NN 256
#define ND 16
#define NC 32

__global__ __launch_bounds__(256) void k1_pre(
    const float* __restrict__ x, const float* __restrict__ W1,
    const float* __restrict__ b1, const float* __restrict__ W2,
    float* __restrict__ A1w, float* __restrict__ W20T, float* __restrict__ W21T,
    float* __restrict__ R1, float* __restrict__ Dg1, float* __restrict__ T1,
    float* __restrict__ Tot1, float* __restrict__ G)
{
    int b = blockIdx.x, t = threadIdx.x;
    __shared__ float sS[ND];
    __shared__ float part[16][ND + 1];
    const float* xb = x + b * NN * ND;

    {   // column sums S[d] = sum_i x[b,i,d]
        int i0 = t >> 4, d = t & 15;
        float p = 0.f;
        #pragma unroll
        for (int k = 0; k < 16; ++k) p += xb[(i0 + (k << 4)) * ND + d];
        part[i0][d] = p;
    }
    __syncthreads();
    if (t < ND) {
        float s = 0.f;
        #pragma unroll
        for (int k = 0; k < 16; ++k) s += part[k][t];
        sS[t] = s;
    }
    __syncthreads();

    // per-row broadcast terms
    int i = t;
    float xi[ND];
    #pragma unroll
    for (int d = 0; d < ND; ++d) xi[d] = xb[i * ND + d];

    for (int c = 0; c < NC; ++c) {
        float r = 0.f, dg = 0.f;
        #pragma unroll
        for (int d = 0; d < ND; ++d) {
            const float* w1a = W1 + d * (NC * 5) + c * 5;          // e = d   (diag part)
            const float* w1b = W1 + (ND + d) * (NC * 5) + c * 5;   // e = 16+d (outer part)
            dg += xi[d] * (w1a[0] + w1a[1] + w1a[2]) + xi[d] * xi[d] * w1b[2];
            r  += xi[d] * w1a[3] + xi[d] * sS[d] * w1b[3];
        }
        R1[(b * NN + i) * NC + c]  = r * (1.0f / 256.0f);
        Dg1[(b * NN + i) * NC + c] = dg;
    }
    if (t < NC) {
        int c = t;
        float tt = 0.f;
        #pragma unroll
        for (int d = 0; d < ND; ++d)
            tt += sS[d] * W1[d * (NC * 5) + c * 5 + 4]
                + sS[d] * sS[d] * W1[(ND + d) * (NC * 5) + c * 5 + 4];
        T1[b * NC + c] = tt * (1.0f / 65536.0f) + b1[c];
        Tot1[b * NC + c] = 0.f;
        G[b * NC + c] = 0.f;
    }
    if (b == 0) {
        if (t < NC) {
            int c = t;
            #pragma unroll
            for (int d = 0; d < ND; ++d)
                A1w[c * ND + d] = W1[(ND + d) * (NC * 5) + c * 5 + 0]
                                + W1[(ND + d) * (NC * 5) + c * 5 + 1];
        }
        for (int k = t; k < NC * NC; k += 256) {
            int s = k >> 5, c = k & 31;
            W20T[k] = W2[c * (NC * 5) + s * 5 + 0];
            W21T[k] = W2[c * (NC * 5) + s * 5 + 1];
        }
    }
}

// Pass 1: row sums / diag / total of h1 (h1 recomputed, not stored).
// Block = (i, b), thread = j.
__global__ __launch_bounds__(256) void k2_rows(
    const float* __restrict__ x, const float* __restrict__ A1w,
    const float* __restrict__ R1, const float* __restrict__ Dg1,
    const float* __restrict__ T1,
    float* __restrict__ Row1, float* __restrict__ Diag1, float* __restrict__ Tot1)
{
    int i = blockIdx.x, b = blockIdx.y, j = threadIdx.x;
    const float* xb = x + b * NN * ND;
    float p[ND];
    #pragma unroll
    for (int d = 0; d < ND; ++d) p[d] = xb[i * ND + d] * xb[j * ND + d];

    const float* R1i = R1 + (b * NN + i) * NC;
    const float* Dgi = Dg1 + (b * NN + i) * NC;
    const float* T1b = T1 + b * NC;
    bool isd = (j == i);
    __shared__ float red[4][NC];
    int wv = j >> 6, ln = j & 63;

    for (int c = 0; c < NC; ++c) {
        float q = 0.f;
        #pragma unroll
        for (int d = 0; d < ND; ++d) q += p[d] * A1w[c * ND + d];
        float val = q + R1i[c] + T1b[c];
        if (isd) val += Dgi[c];
        val = fmaxf(val, 0.f);
        if (isd) Diag1[(b * NN + i) * NC + c] = val;
        float v = val;
        #pragma unroll
        for (int off = 32; off > 0; off >>= 1) v += __shfl_down(v, off, 64);
        if (ln == 0) red[wv][c] = v;
    }
    __syncthreads();
    if (j < NC) {
        float v = red[0][j] + red[1][j] + red[2][j] + red[3][j];
        Row1[(b * NN + i) * NC + j] = v;
        atomicAdd(&Tot1[b * NC + j], v);
    }
}

// Layer-2 broadcast constants.
__global__ __launch_bounds__(256) void k3_const(
    const float* __restrict__ W2, const float* __restrict__ b2,
    const float* __restrict__ Row1, const float* __restrict__ Diag1,
    const float* __restrict__ Tot1,
    float* __restrict__ CD2, float* __restrict__ CR2, float* __restrict__ CT2)
{
    int b = blockIdx.x, i = threadIdx.x;
    float dgv[NC], rwv[NC];
    #pragma unroll
    for (int c = 0; c < NC; ++c) {
        dgv[c] = Diag1[(b * NN + i) * NC + c];
        rwv[c] = Row1[(b * NN + i) * NC + c];
    }
    for (int s = 0; s < NC; ++s) {
        float cd = 0.f, cr = 0.f;
        #pragma unroll
        for (int c = 0; c < NC; ++c) {
            cd += dgv[c] * W2[c * (NC * 5) + s * 5 + 2];
            cr += rwv[c] * W2[c * (NC * 5) + s * 5 + 3];
        }
        CD2[(b * NN + i) * NC + s] = cd;
        CR2[(b * NN + i) * NC + s] = cr * (1.0f / 256.0f);
    }
    if (i < NC) {
        int s = i;
        float ct = 0.f;
        #pragma unroll
        for (int c = 0; c < NC; ++c) ct += Tot1[b * NC + c] * W2[c * (NC * 5) + s * 5 + 4];
        CT2[b * NC + s] = ct * (1.0f / 65536.0f) + b2[s];
    }
}

// Pass 2: fused layer2 + relu + spatial reduction over unordered 16x16 tile pairs.
// Block handles tile (TI,TJ) and its mirror (TJ,TI) from the same recomputed h1 values.
__global__ __launch_bounds__(256) void k4_main(
    const float* __restrict__ x, const float* __restrict__ A1w,
    const float* __restrict__ R1, const float* __restrict__ Dg1,
    const float* __restrict__ T1, const float* __restrict__ W20T,
    const float* __restrict__ W21T, const float* __restrict__ CD2,
    const float* __restrict__ CR2, const float* __restrict__ CT2,
    float* __restrict__ G)
{
    int b = blockIdx.y;
    int idx = blockIdx.x;
    int TI = 0, rem = idx;
    while (rem >= 16 - TI) { rem -= 16 - TI; ++TI; }
    int TJ = TI + rem;

    int t = threadIdx.x;
    int ti = t >> 4, tj = t & 15;
    int i = TI * 16 + ti, j = TJ * 16 + tj;
    const float* xb = x + b * NN * ND;

    float p[ND];
    #pragma unroll
    for (int d = 0; d < ND; ++d) p[d] = xb[i * ND + d] * xb[j * ND + d];

    const float* T1b = T1 + b * NC;
    const float* R1i = R1 + (b * NN + i) * NC;
    const float* R1j = R1 + (b * NN + j) * NC;
    bool dgf = (i == j);

    float hA[NC], hB[NC];
    #pragma unroll
    for (int c = 0; c < NC; ++c) {
        float q = 0.f;
        #pragma unroll
        for (int d = 0; d < ND; ++d) q += p[d] * A1w[c * ND + d];
        float base = q + T1b[c];
        float vA = base + R1i[c];
        float vB = base + R1j[c];
        if (dgf) { vA += Dg1[(b * NN + i) * NC + c]; vB = vA; }
        hA[c] = fmaxf(vA, 0.f);
        hB[c] = fmaxf(vB, 0.f);
    }

    const float* CR2i = CR2 + (b * NN + i) * NC;
    const float* CR2j = CR2 + (b * NN + j) * NC;
    const float* CD2i = CD2 + (b * NN + i) * NC;
    const float* CT2b = CT2 + b * NC;
    bool mirror = (TI != TJ);

    __shared__ float red[4][NC];
    int wv = t >> 6, ln = t & 63;

    for (int s = 0; s < NC; ++s) {
        float a1 = CR2i[s] + CT2b[s];
        if (dgf) a1 += CD2i[s];
        float a2 = CR2j[s] + CT2b[s];
        #pragma unroll
        for (int c = 0; c < NC; ++c) {
            float w0 = W20T[s * NC + c], w1 = W21T[s * NC + c];
            a1 += hA[c] * w0 + hB[c] * w1;
            a2 += hB[c] * w0 + hA[c] * w1;
        }
        float r = fmaxf(a1, 0.f);
        if (mirror) r += fmaxf(a2, 0.f);
        float v = r;
        #pragma unroll
        for (int off = 32; off > 0; off >>= 1) v += __shfl_down(v, off, 64);
        if (ln == 0) red[wv][s] = v;
    }
    __syncthreads();
    if (t < NC) {
        float v = red[0][t] + red[1][t] + red[2][t] + red[3][t];
        atomicAdd(&G[b * NC + t], v);
    }
}

// Tiny decoder MLP: relu(g) -> 128 -> 128 -> 1.
__global__ __launch_bounds__(128) void k5_mlp(
    const float* __restrict__ G, const float* __restrict__ D1, const float* __restrict__ db1,
    const float* __restrict__ D2, const float* __restrict__ db2,
    const float* __restrict__ D3, const float* __restrict__ db3,
    float* __restrict__ out)
{
    int b = blockIdx.x, t = threadIdx.x;
    __shared__ float a[NC], h2s[128], r2[2];
    if (t < NC) a[t] = fmaxf(G[b * NC + t], 0.f);
    __syncthreads();
    float acc = db1[t];
    #pragma unroll
    for (int s = 0; s < NC; ++s) acc += a[s] * D1[s * 128 + t];
    float h2 = fmaxf(acc, 0.f);
    h2s[t] = h2;
    __syncthreads();
    float acc2 = db2[t];
    for (int u = 0; u < 128; ++u) acc2 += h2s[u] * D2[u * 128 + t];
    float h3 = fmaxf(acc2, 0.f);
    float v = h3 * D3[t];
    #pragma unroll
    for (int off = 32; off > 0; off >>= 1) v += __shfl_down(v, off, 64);
    if ((t & 63) == 0) r2[t >> 6] = v;
    __syncthreads();
    if (t == 0) out[b] = r2[0] + r2[1] + db3[0];
}

extern "C" void kernel_launch(void* const* d_in, const int* in_sizes, int n_in,
                              void* d_out, int out_size, void* d_ws, size_t ws_size,
                              hipStream_t stream)
{
    const float* x   = (const float*)d_in[0];
    const float* W1  = (const float*)d_in[1];
    const float* b1  = (const float*)d_in[2];
    const float* W2  = (const float*)d_in[3];
    const float* b2  = (const float*)d_in[4];
    const float* D1  = (const float*)d_in[5];
    const float* db1 = (const float*)d_in[6];
    const float* D2  = (const float*)d_in[7];
    const float* db2 = (const float*)d_in[8];
    const float* D3  = (const float*)d_in[9];
    const float* db3 = (const float*)d_in[10];
    float* out = (float*)d_out;

    float* w = (float*)d_ws;
    float* pA1w  = w; w += NC * ND;        // 512
    float* pW20T = w; w += NC * NC;        // 1024
    float* pW21T = w; w += NC * NC;        // 1024
    float* pR1   = w; w += NB * NN * NC;   // 65536
    float* pDg1  = w; w += NB * NN * NC;
    float* pT1   = w; w += NB * NC;        // 256
    float* pRow1 = w; w += NB * NN * NC;
    float* pDiag1= w; w += NB * NN * NC;
    float* pTot1 = w; w += NB * NC;
    float* pCD2  = w; w += NB * NN * NC;
    float* pCR2  = w; w += NB * NN * NC;
    float* pCT2  = w; w += NB * NC;
    float* pG    = w; w += NB * NC;

    hipLaunchKernelGGL(k1_pre, dim3(NB), dim3(256), 0, stream,
                       x, W1, b1, W2, pA1w, pW20T, pW21T, pR1, pDg1, pT1, pTot1, pG);
    hipLaunchKernelGGL(k2_rows, dim3(NN, NB), dim3(256), 0, stream,
                       x, pA1w, pR1, pDg1, pT1, pRow1, pDiag1, pTot1);
    hipLaunchKernelGGL(k3_const, dim3(NB), dim3(256), 0, stream,
                       W2, b2, pRow1, pDiag1, pTot1, pCD2, pCR2, pCT2);
    hipLaunchKernelGGL(k4_main, dim3(136, NB), dim3(256), 0, stream,
                       x, pA1w, pR1, pDg1, pT1, pW20T, pW21T, pCD2, pCR2, pCT2, pG);
    hipLaunchKernelGGL(k5_mlp, dim3(NB), dim3(128), 0, stream,
                       pG, D1, db1, D2, db2, D3, db3, out);
}

// Round 2
// 203.187 us; speedup vs baseline: 1.4690x; 1.4690x over previous
//
#include <hip/hip_runtime.h>
#include <hip/hip_bf16.h>

// MiniEq2Net fully-fused fp32 implementation, round 2.
// B=8, n=256, nin=16, C=nhid=32, DH=128.
//
//   h1[c,i,j] = relu( Q[c,i,j] + R1[c,i] + T1[c] + (i==j)*Dg1[c,i] )
//     Q[c,i,j]  = sum_d x[i,d] x[j,d] * A1w[c,d],  A1w = W1[16+d,c,0]+W1[16+d,c,1]
//   out2[s,i,j] = sum_c h1[c,i,j]*W20T[s,c] + h1[c,j,i]*W21T[s,c]
//               + (i==j)*CD2[s,i] + CR2[s,i] + CT2[s]
//   g[b,s] = sum_ij relu(out2); then MLP 32->128->128->1.
//
// Round-2 change: all weight combos precomputed ONCE (kB block 0); per-row
// glue (R1/Dg1/CD2/CR2) distributed across the 2048-block row kernel kC;
// CT2 folded into kD's preamble. Kills the two 8-block latency-bound kernels
// that were 0.35% occupancy / ~100 us each.

#define NB 8
#define NN 256
#define ND 16
#define NC 32
#define W1S (NC * 5)   // 160: stride of W1's leading dim

// kB: per-batch column sums S, T1, zero Tot1/G; block 0 also builds all
// combined-weight tables (tiny).
__global__ __launch_bounds__(256) void kB_pre(
    const float* __restrict__ x, const float* __restrict__ W1,
    const float* __restrict__ b1, const float* __restrict__ W2,
    float* __restrict__ S, float* __restrict__ T1,
    float* __restrict__ Tot1, float* __restrict__ G,
    float* __restrict__ A1w, float* __restrict__ wDgA, float* __restrict__ wDgB,
    float* __restrict__ wRA, float* __restrict__ wRB,
    float* __restrict__ W20T, float* __restrict__ W21T,
    float* __restrict__ W2d, float* __restrict__ W2r, float* __restrict__ W2t)
{
    int b = blockIdx.x, t = threadIdx.x;
    __shared__ float part[16][ND + 1];
    __shared__ float sS[ND];
    const float* xb = x + b * NN * ND;

    {   // column sums S[d] = sum_i x[b,i,d]
        int i0 = t >> 4, d = t & 15;
        float p = 0.f;
        #pragma unroll
        for (int k = 0; k < 16; ++k) p += xb[(i0 + (k << 4)) * ND + d];
        part[i0][d] = p;
    }
    __syncthreads();
    if (t < ND) {
        float s = 0.f;
        #pragma unroll
        for (int k = 0; k < 16; ++k) s += part[k][t];
        sS[t] = s;
        S[b * ND + t] = s;
    }
    __syncthreads();
    if (t < NC) {
        int c = t;
        float tt = 0.f;
        #pragma unroll
        for (int d = 0; d < ND; ++d)
            tt += sS[d] * W1[d * W1S + c * 5 + 4]
                + sS[d] * sS[d] * W1[(ND + d) * W1S + c * 5 + 4];
        T1[b * NC + c] = tt * (1.0f / 65536.0f) + b1[c];
        Tot1[b * NC + c] = 0.f;
        G[b * NC + c] = 0.f;
    }
    if (b == 0) {
        for (int k = t; k < NC * ND; k += 256) {     // [c][d] tables
            int c = k >> 4, d = k & 15;
            const float* wa = W1 + d * W1S + c * 5;          // e = d
            const float* wb = W1 + (ND + d) * W1S + c * 5;   // e = 16+d
            A1w[k]  = wb[0] + wb[1];
            wDgA[k] = wa[0] + wa[1] + wa[2];
            wDgB[k] = wb[2];
            wRA[k]  = wa[3];
            wRB[k]  = wb[3];
        }
        for (int k = t; k < NC * NC; k += 256) {     // [s][c] tables
            int s = k >> 5, c = k & 31;
            const float* w = W2 + c * W1S + s * 5;
            W20T[k] = w[0];
            W21T[k] = w[1];
            W2d[k]  = w[2];
            W2r[k]  = w[3];
            W2t[k]  = w[4];
        }
    }
}

// kC: one block per (row i, batch b). Computes R1/Dg1 for the row, then the
// row's h1 (recomputed, not stored), reduces it to Row/Diag/Tot, then the
// layer-2 broadcast constants CD2/CR2 for the row.
__global__ __launch_bounds__(256) void kC_rows(
    const float* __restrict__ x, const float* __restrict__ S,
    const float* __restrict__ T1, const float* __restrict__ A1w,
    const float* __restrict__ wDgA, const float* __restrict__ wDgB,
    const float* __restrict__ wRA, const float* __restrict__ wRB,
    const float* __restrict__ W2d, const float* __restrict__ W2r,
    float* __restrict__ R1, float* __restrict__ Dg1, float* __restrict__ Tot1,
    float* __restrict__ CD2, float* __restrict__ CR2)
{
    int i = blockIdx.x, b = blockIdx.y, t = threadIdx.x;
    __shared__ float sXi[ND], sS[ND], sT1[NC], sR1[NC], sDg[NC];
    __shared__ float red[4][NC];
    __shared__ float sRow[NC], sDiag[NC];
    const float* xb = x + b * NN * ND;

    if (t < ND) { sXi[t] = xb[i * ND + t]; sS[t] = S[b * ND + t]; }
    if (t >= 64 && t < 64 + NC) sT1[t - 64] = T1[b * NC + (t - 64)];

    int j = t;
    float xj[ND];
    #pragma unroll
    for (int d = 0; d < ND; ++d) xj[d] = xb[j * ND + d];
    __syncthreads();

    float p[ND];
    #pragma unroll
    for (int d = 0; d < ND; ++d) p[d] = sXi[d] * xj[d];

    if (t < NC) {   // row broadcast terms from precombined tables
        int c = t;
        float r = 0.f, dg = 0.f;
        #pragma unroll
        for (int d = 0; d < ND; ++d) {
            float xi = sXi[d];
            dg += xi * wDgA[c * ND + d] + xi * xi * wDgB[c * ND + d];
            r  += xi * wRA[c * ND + d] + xi * sS[d] * wRB[c * ND + d];
        }
        r *= (1.0f / 256.0f);
        sR1[c] = r; sDg[c] = dg;
        R1[(b * NN + i) * NC + c] = r;
        Dg1[(b * NN + i) * NC + c] = dg;
    }
    __syncthreads();

    bool isd = (j == i);
    int wv = t >> 6, ln = t & 63;
    for (int c = 0; c < NC; ++c) {
        float q = 0.f;
        #pragma unroll
        for (int d = 0; d < ND; ++d) q += p[d] * A1w[c * ND + d];
        float val = q + sR1[c] + sT1[c];
        if (isd) val += sDg[c];
        val = fmaxf(val, 0.f);
        if (isd) sDiag[c] = val;
        float v = val;
        #pragma unroll
        for (int off = 32; off > 0; off >>= 1) v += __shfl_down(v, off, 64);
        if (ln == 0) red[wv][c] = v;
    }
    __syncthreads();
    if (t < NC) {
        float row = red[0][t] + red[1][t] + red[2][t] + red[3][t];
        sRow[t] = row;
        atomicAdd(&Tot1[b * NC + t], row);
    }
    __syncthreads();
    if (t < NC) {
        int s = t;
        float cd = 0.f, cr = 0.f;
        #pragma unroll
        for (int c = 0; c < NC; ++c) {
            cd += sDiag[c] * W2d[s * NC + c];
            cr += sRow[c] * W2r[s * NC + c];
        }
        CD2[(b * NN + i) * NC + s] = cd;
        CR2[(b * NN + i) * NC + s] = cr * (1.0f / 256.0f);
    }
}

// kD: fused layer2 + relu + spatial reduction over unordered 16x16 tile pairs.
// CT2 computed redundantly per block in the preamble (trivial).
__global__ __launch_bounds__(256) void kD_main(
    const float* __restrict__ x, const float* __restrict__ A1w,
    const float* __restrict__ R1, const float* __restrict__ Dg1,
    const float* __restrict__ T1, const float* __restrict__ W20T,
    const float* __restrict__ W21T, const float* __restrict__ CD2,
    const float* __restrict__ CR2, const float* __restrict__ W2t,
    const float* __restrict__ b2, const float* __restrict__ Tot1,
    float* __restrict__ G)
{
    int b = blockIdx.y;
    int idx = blockIdx.x;
    int TI = 0, rem = idx;
    while (rem >= 16 - TI) { rem -= 16 - TI; ++TI; }
    int TJ = TI + rem;

    int t = threadIdx.x;
    int ti = t >> 4, tj = t & 15;
    int i = TI * 16 + ti, j = TJ * 16 + tj;
    const float* xb = x + b * NN * ND;

    __shared__ float sCT2[NC];
    __shared__ float red[4][NC];
    if (t < NC) {
        int s = t;
        float ct = 0.f;
        #pragma unroll
        for (int c = 0; c < NC; ++c) ct += Tot1[b * NC + c] * W2t[s * NC + c];
        sCT2[s] = ct * (1.0f / 65536.0f) + b2[s];
    }

    float p[ND];
    #pragma unroll
    for (int d = 0; d < ND; ++d) p[d] = xb[i * ND + d] * xb[j * ND + d];

    const float* T1b = T1 + b * NC;
    const float* R1i = R1 + (b * NN + i) * NC;
    const float* R1j = R1 + (b * NN + j) * NC;
    bool dgf = (i == j);

    float hA[NC], hB[NC];
    #pragma unroll
    for (int c = 0; c < NC; ++c) {
        float q = 0.f;
        #pragma unroll
        for (int d = 0; d < ND; ++d) q += p[d] * A1w[c * ND + d];
        float base = q + T1b[c];
        float vA = base + R1i[c];
        float vB = base + R1j[c];
        if (dgf) { vA += Dg1[(b * NN + i) * NC + c]; vB = vA; }
        hA[c] = fmaxf(vA, 0.f);
        hB[c] = fmaxf(vB, 0.f);
    }

    const float* CR2i = CR2 + (b * NN + i) * NC;
    const float* CR2j = CR2 + (b * NN + j) * NC;
    const float* CD2i = CD2 + (b * NN + i) * NC;
    bool mirror = (TI != TJ);
    __syncthreads();

    int wv = t >> 6, ln = t & 63;
    for (int s = 0; s < NC; ++s) {
        float a1 = CR2i[s] + sCT2[s];
        if (dgf) a1 += CD2i[s];
        float a2 = CR2j[s] + sCT2[s];
        #pragma unroll
        for (int c = 0; c < NC; ++c) {
            float w0 = W20T[s * NC + c], w1 = W21T[s * NC + c];
            a1 += hA[c] * w0 + hB[c] * w1;
            a2 += hB[c] * w0 + hA[c] * w1;
        }
        float r = fmaxf(a1, 0.f);
        if (mirror) r += fmaxf(a2, 0.f);
        float v = r;
        #pragma unroll
        for (int off = 32; off > 0; off >>= 1) v += __shfl_down(v, off, 64);
        if (ln == 0) red[wv][s] = v;
    }
    __syncthreads();
    if (t < NC) {
        float v = red[0][t] + red[1][t] + red[2][t] + red[3][t];
        atomicAdd(&G[b * NC + t], v);
    }
}

// Tiny decoder MLP: relu(g) -> 128 -> 128 -> 1.
__global__ __launch_bounds__(128) void k5_mlp(
    const float* __restrict__ G, const float* __restrict__ D1, const float* __restrict__ db1,
    const float* __restrict__ D2, const float* __restrict__ db2,
    const float* __restrict__ D3, const float* __restrict__ db3,
    float* __restrict__ out)
{
    int b = blockIdx.x, t = threadIdx.x;
    __shared__ float a[NC], h2s[128], r2[2];
    if (t < NC) a[t] = fmaxf(G[b * NC + t], 0.f);
    __syncthreads();
    float acc = db1[t];
    #pragma unroll
    for (int s = 0; s < NC; ++s) acc += a[s] * D1[s * 128 + t];
    float h2 = fmaxf(acc, 0.f);
    h2s[t] = h2;
    __syncthreads();
    float acc2 = db2[t];
    for (int u = 0; u < 128; ++u) acc2 += h2s[u] * D2[u * 128 + t];
    float h3 = fmaxf(acc2, 0.f);
    float v = h3 * D3[t];
    #pragma unroll
    for (int off = 32; off > 0; off >>= 1) v += __shfl_down(v, off, 64);
    if ((t & 63) == 0) r2[t >> 6] = v;
    __syncthreads();
    if (t == 0) out[b] = r2[0] + r2[1] + db3[0];
}

extern "C" void kernel_launch(void* const* d_in, const int* in_sizes, int n_in,
                              void* d_out, int out_size, void* d_ws, size_t ws_size,
                              hipStream_t stream)
{
    const float* x   = (const float*)d_in[0];
    const float* W1  = (const float*)d_in[1];
    const float* b1  = (const float*)d_in[2];
    const float* W2  = (const float*)d_in[3];
    const float* b2  = (const float*)d_in[4];
    const float* D1  = (const float*)d_in[5];
    const float* db1 = (const float*)d_in[6];
    const float* D2  = (const float*)d_in[7];
    const float* db2 = (const float*)d_in[8];
    const float* D3  = (const float*)d_in[9];
    const float* db3 = (const float*)d_in[10];
    float* out = (float*)d_out;

    float* w = (float*)d_ws;
    float* pA1w  = w; w += NC * ND;
    float* pWDgA = w; w += NC * ND;
    float* pWDgB = w; w += NC * ND;
    float* pWRA  = w; w += NC * ND;
    float* pWRB  = w; w += NC * ND;
    float* pW20T = w; w += NC * NC;
    float* pW21T = w; w += NC * NC;
    float* pW2d  = w; w += NC * NC;
    float* pW2r  = w; w += NC * NC;
    float* pW2t  = w; w += NC * NC;
    float* pS    = w; w += NB * ND;
    float* pT1   = w; w += NB * NC;
    float* pR1   = w; w += NB * NN * NC;
    float* pDg1  = w; w += NB * NN * NC;
    float* pTot1 = w; w += NB * NC;
    float* pCD2  = w; w += NB * NN * NC;
    float* pCR2  = w; w += NB * NN * NC;
    float* pG    = w; w += NB * NC;

    hipLaunchKernelGGL(kB_pre, dim3(NB), dim3(256), 0, stream,
                       x, W1, b1, W2, pS, pT1, pTot1, pG,
                       pA1w, pWDgA, pWDgB, pWRA, pWRB, pW20T, pW21T, pW2d, pW2r, pW2t);
    hipLaunchKernelGGL(kC_rows, dim3(NN, NB), dim3(256), 0, stream,
                       x, pS, pT1, pA1w, pWDgA, pWDgB, pWRA, pWRB, pW2d, pW2r,
                       pR1, pDg1, pTot1, pCD2, pCR2);
    hipLaunchKernelGGL(kD_main, dim3(136, NB), dim3(256), 0, stream,
                       x, pA1w, pR1, pDg1, pT1, pW20T, pW21T, pCD2, pCR2, pW2t, b2, pTot1, pG);
    hipLaunchKernelGGL(k5_mlp, dim3(NB), dim3(128), 0, stream,
                       pG, D1, db1, D2, db2, D3, db3, out);
}

// Round 3
// 123.209 us; speedup vs baseline: 2.4225x; 1.6491x over previous
//
#include <hip/hip_runtime.h>
#include <hip/hip_bf16.h>

// MiniEq2Net round 3: MFMA (bf16 16x16x32) for the two matmul-shaped
// contractions; fp32 epilogues. B=8, n=256, nin=16, C=32, DH=128.
//
//   h1[c,i,j] = relu( Q[c,i,j] + R1[c,i] + T1[c] + (i==j)*Dg1[c,i] )
//     Q = p[pos x 16d] . A1w[16d x 32c],  p_d = x[i,d]*x[j,d]   (symmetric)
//   out2(i,j)[s] = sum_c hA[c]*W0[c,s] + hB[c]*W1[c,s] + bcast
//     u=hA+hB, v=hA-hB, Wp=(W0+W1)/2, Wm=(W0-W1)/2:
//     a1 = u.Wp + v.Wm (+bcast_i), a2 = u.Wp - v.Wm (+bcast_j)
//   g[b,s] = sum_ij relu(out2); then MLP 32->128->128->1.
//
// MFMA layouts (gfx950, guide-verified):
//   A: A[m][k], m=lane&15, k=(lane>>4)*8+j (j=0..7 contiguous)
//   B: B[k][n], n=lane&15, k=(lane>>4)*8+j
//   C/D: col=lane&15, row=(lane>>4)*4+reg
// T1 (+R1i in kC) folded into k=16 slot with constant-1.0 A entry.

#define NB 8
#define NN 256
#define ND 16
#define NC 32
#define W1S (NC * 5)   // 160

using bf16x8 = __attribute__((ext_vector_type(8))) __bf16;
using f32x4  = __attribute__((ext_vector_type(4))) float;

#define MFMA(a, b, c) __builtin_amdgcn_mfma_f32_16x16x32_bf16((a), (b), (c), 0, 0, 0)

// ---------------- kB: per-batch S/T1, zero Tot1/G, weight tables ------------
__global__ __launch_bounds__(256) void kB_pre(
    const float* __restrict__ x, const float* __restrict__ W1,
    const float* __restrict__ b1, const float* __restrict__ W2,
    float* __restrict__ S, float* __restrict__ T1,
    float* __restrict__ Tot1, float* __restrict__ G,
    float* __restrict__ W2dT, float* __restrict__ W2rT, float* __restrict__ W2tT,
    __bf16* __restrict__ A1wT, __bf16* __restrict__ WpT, __bf16* __restrict__ WmT)
{
    int b = blockIdx.x, t = threadIdx.x;
    __shared__ float part[16][ND + 1];
    __shared__ float sS[ND];
    const float* xb = x + b * NN * ND;

    { int i0 = t >> 4, d = t & 15; float p = 0.f;
      #pragma unroll
      for (int k = 0; k < 16; ++k) p += xb[(i0 + (k << 4)) * ND + d];
      part[i0][d] = p; }
    __syncthreads();
    if (t < ND) { float s = 0.f;
      #pragma unroll
      for (int k = 0; k < 16; ++k) s += part[k][t];
      sS[t] = s; S[b * ND + t] = s; }
    __syncthreads();
    if (t < NC) { int c = t; float tt = 0.f;
      #pragma unroll
      for (int d = 0; d < ND; ++d)
        tt += sS[d] * W1[d * W1S + c * 5 + 4]
            + sS[d] * sS[d] * W1[(ND + d) * W1S + c * 5 + 4];
      T1[b * NC + c] = tt * (1.f / 65536.f) + b1[c];
      Tot1[b * NC + c] = 0.f; G[b * NC + c] = 0.f; }
    if (b == 0) {
      for (int k = t; k < NC * ND; k += 256) {
        int c = k >> 4, d = k & 15;
        A1wT[k] = (__bf16)(W1[(ND + d) * W1S + c * 5 + 0]
                         + W1[(ND + d) * W1S + c * 5 + 1]);
      }
      for (int k = t; k < NC * NC; k += 256) {
        int s = k >> 5, c = k & 31;
        const float* w = W2 + c * W1S + s * 5;
        float w0 = w[0], w1 = w[1];
        WpT[k] = (__bf16)((w0 + w1) * 0.5f);
        WmT[k] = (__bf16)((w0 - w1) * 0.5f);
        W2dT[k] = w[2]; W2rT[k] = w[3]; W2tT[k] = w[4];
      }
    }
}

// ---------------- kC: per-(b,i) row pass — MFMA Q, row/diag sums, CD2/CR2 ---
__global__ __launch_bounds__(256) void kC_rows(
    const float* __restrict__ x, const float* __restrict__ W1,
    const float* __restrict__ Sg, const float* __restrict__ T1g,
    const __bf16* __restrict__ A1wT,
    const float* __restrict__ W2dT, const float* __restrict__ W2rT,
    float* __restrict__ R1, float* __restrict__ Dg1, float* __restrict__ Tot1,
    float* __restrict__ CD2, float* __restrict__ CR2)
{
    const int i = blockIdx.x, b = blockIdx.y, t = threadIdx.x;
    __shared__ __align__(16) float  sX[NN][ND];    // 16 KB
    __shared__ __align__(16) __bf16 sPA[NN][40];   // 20 KB (row stride 80 B)
    __shared__ __align__(16) __bf16 sBQ[NC][40];   // 2.5 KB
    __shared__ float sS[ND], sDg[NC], sDiag[NC], sRow[NC];
    __shared__ float red[4][NC];

    { const float4* xb4 = (const float4*)(x + b * NN * ND);
      float4* sX4 = (float4*)&sX[0][0];
      #pragma unroll
      for (int kk = 0; kk < 4; ++kk) sX4[t + kk * 256] = xb4[t + kk * 256]; }
    if (t < ND) sS[t] = Sg[b * ND + t];
    for (int kk = 0; kk < 2; ++kk) {
      int idx = t + kk * 256; int c = idx >> 4, k = idx & 15;
      sBQ[c][k] = A1wT[idx];
    }
    __syncthreads();

    if (t < NC) {   // row broadcast terms (raw W1, L2-hot) + fold into B table
      int c = t; float r = 0.f, dg = 0.f;
      #pragma unroll
      for (int d = 0; d < ND; ++d) {
        float xi = sX[i][d];
        r  += xi * W1[d * W1S + c * 5 + 3]
            + xi * sS[d] * W1[(ND + d) * W1S + c * 5 + 3];
        dg += xi * (W1[d * W1S + c * 5 + 0] + W1[d * W1S + c * 5 + 1]
                  + W1[d * W1S + c * 5 + 2])
            + xi * xi * W1[(ND + d) * W1S + c * 5 + 2];
      }
      r *= (1.f / 256.f);
      R1[(b * NN + i) * NC + c] = r;
      Dg1[(b * NN + i) * NC + c] = dg;
      sDg[c] = dg;
      sBQ[c][16] = (__bf16)(T1g[b * NC + c] + r);
      #pragma unroll
      for (int k = 17; k < 32; ++k) sBQ[c][k] = (__bf16)0.f;
    }
    {   // p row for this thread's position j=t  (A-slot 16 = 1.0 for the fold)
      #pragma unroll
      for (int d = 0; d < ND; ++d) sPA[t][d] = (__bf16)(sX[i][d] * sX[t][d]);
      sPA[t][16] = (__bf16)1.f;
      #pragma unroll
      for (int k = 17; k < 32; ++k) sPA[t][k] = (__bf16)0.f;
    }
    __syncthreads();

    const int wv = t >> 6, ln = t & 63;
    const int m = ln & 15, quad = ln >> 4;
    const int c0 = m, c1 = m + 16;
    f32x4 zero = {0.f, 0.f, 0.f, 0.f};
    bf16x8 bq0 = *(const bf16x8*)&sBQ[c0][8 * quad];
    bf16x8 bq1 = *(const bf16x8*)&sBQ[c1][8 * quad];
    float rsum0 = 0.f, rsum1 = 0.f;
    #pragma unroll
    for (int gg = 0; gg < 4; ++gg) {
      int g = wv * 4 + gg;
      bf16x8 av = *(const bf16x8*)&sPA[g * 16 + m][8 * quad];
      f32x4 q0 = MFMA(av, bq0, zero);
      f32x4 q1 = MFMA(av, bq1, zero);
      #pragma unroll
      for (int r = 0; r < 4; ++r) {
        int pos = g * 16 + quad * 4 + r;       // = j
        float v0 = q0[r], v1 = q1[r];
        if (pos == i) { v0 += sDg[c0]; v1 += sDg[c1]; }
        float h0 = fmaxf(v0, 0.f), h1 = fmaxf(v1, 0.f);
        if (pos == i) { sDiag[c0] = h0; sDiag[c1] = h1; }
        rsum0 += h0; rsum1 += h1;
      }
    }
    rsum0 += __shfl_down(rsum0, 32, 64); rsum0 += __shfl_down(rsum0, 16, 64);
    rsum1 += __shfl_down(rsum1, 32, 64); rsum1 += __shfl_down(rsum1, 16, 64);
    if (ln < 16) { red[wv][ln] = rsum0; red[wv][ln + 16] = rsum1; }
    __syncthreads();
    if (t < NC) {
      float Row = red[0][t] + red[1][t] + red[2][t] + red[3][t];
      sRow[t] = Row;
      atomicAdd(&Tot1[b * NC + t], Row);
    }
    __syncthreads();
    if (t < NC) {
      int s = t; float cd = 0.f, cr = 0.f;
      #pragma unroll
      for (int c = 0; c < NC; ++c) {
        cd += sDiag[c] * W2dT[s * NC + c];
        cr += sRow[c]  * W2rT[s * NC + c];
      }
      CD2[(b * NN + i) * NC + s] = cd;
      CR2[(b * NN + i) * NC + s] = cr * (1.f / 256.f);
    }
}

// ---------------- kD: tile-pair fused layer1+layer2+reduce (MFMA) -----------
__global__ __launch_bounds__(256) void kD_main(
    const float* __restrict__ x, const float* __restrict__ R1g,
    const float* __restrict__ Dg1g, const float* __restrict__ T1g,
    const float* __restrict__ CD2g, const float* __restrict__ CR2g,
    const float* __restrict__ Tot1g, const float* __restrict__ W2tT,
    const float* __restrict__ b2,
    const __bf16* __restrict__ A1wT, const __bf16* __restrict__ WpT,
    const __bf16* __restrict__ WmT,
    float* __restrict__ G)
{
    const int b = blockIdx.y, t = threadIdx.x;
    int TI = 0, rem = blockIdx.x;
    while (rem >= 16 - TI) { rem -= 16 - TI; ++TI; }
    const int TJ = TI + rem;
    const bool diagblk = (TI == TJ), mirror = (TI != TJ);

    __shared__ __align__(16) __bf16 sPA[NN][40];   // p, then overwritten by U
    __shared__ __align__(16) __bf16 sV[NN][40];
    __shared__ __align__(16) __bf16 sBQ[NC][40];
    __shared__ __align__(16) __bf16 sWp[NC][40];
    __shared__ __align__(16) __bf16 sWm[NC][40];
    __shared__ float sXI[16][ND], sXJ[16][ND];
    __shared__ float sR1I[16][NC], sR1J[16][NC];
    __shared__ float sCR2I[16][NC], sCR2J[16][NC];
    __shared__ float sCD2I[16][NC], sDgI[16][NC];
    __shared__ float sCT2[NC];
    __shared__ float red[4][NC];

    { int r = t >> 4, d = t & 15;
      sXI[r][d] = x[(b * NN + TI * 16 + r) * ND + d];
      sXJ[r][d] = x[(b * NN + TJ * 16 + r) * ND + d]; }
    #pragma unroll
    for (int kk = 0; kk < 2; ++kk) {
      int idx = t + kk * 256; int r = idx >> 5, c = idx & 31;
      sR1I[r][c]  = R1g [(b * NN + TI * 16 + r) * NC + c];
      sR1J[r][c]  = R1g [(b * NN + TJ * 16 + r) * NC + c];
      sCR2I[r][c] = CR2g[(b * NN + TI * 16 + r) * NC + c];
      sCR2J[r][c] = CR2g[(b * NN + TJ * 16 + r) * NC + c];
      sCD2I[r][c] = CD2g[(b * NN + TI * 16 + r) * NC + c];
      sDgI[r][c]  = Dg1g[(b * NN + TI * 16 + r) * NC + c];
    }
    #pragma unroll
    for (int kk = 0; kk < 2; ++kk) {
      int idx = t + kk * 256; int c = idx >> 4, k = idx & 15;
      sBQ[c][k] = A1wT[idx];
    }
    if (t < NC) {
      sBQ[t][16] = (__bf16)T1g[b * NC + t];
      #pragma unroll
      for (int k = 17; k < 32; ++k) sBQ[t][k] = (__bf16)0.f;
    }
    #pragma unroll
    for (int kk = 0; kk < 4; ++kk) {
      int idx = t + kk * 256; int s = idx >> 5, c = idx & 31;
      sWp[s][c] = WpT[idx]; sWm[s][c] = WmT[idx];
    }
    if (t < NC) {
      float ct = 0.f;
      #pragma unroll
      for (int c = 0; c < NC; ++c) ct += Tot1g[b * NC + c] * W2tT[t * NC + c];
      sCT2[t] = ct * (1.f / 65536.f) + b2[t];
    }
    __syncthreads();

    {   // p row for position (ti,tj) = (t>>4, t&15)
      int ti = t >> 4, tj = t & 15;
      #pragma unroll
      for (int d = 0; d < ND; ++d) sPA[t][d] = (__bf16)(sXI[ti][d] * sXJ[tj][d]);
      sPA[t][16] = (__bf16)1.f;
      #pragma unroll
      for (int k = 17; k < 32; ++k) sPA[t][k] = (__bf16)0.f;
    }
    __syncthreads();

    const int wv = t >> 6, ln = t & 63;
    const int m = ln & 15, quad = ln >> 4;
    const int c0 = m, c1 = m + 16;
    f32x4 zero = {0.f, 0.f, 0.f, 0.f};

    // ---- layer-1: Q' = Q + T1; build u,v (U overwrites sPA in-place) ----
    {
      bf16x8 bq0 = *(const bf16x8*)&sBQ[c0][8 * quad];
      bf16x8 bq1 = *(const bf16x8*)&sBQ[c1][8 * quad];
      #pragma unroll
      for (int gg = 0; gg < 4; ++gg) {
        int g = wv * 4 + gg;
        bf16x8 av = *(const bf16x8*)&sPA[g * 16 + m][8 * quad];
        f32x4 q0 = MFMA(av, bq0, zero);
        f32x4 q1 = MFMA(av, bq1, zero);
        float r1i0 = sR1I[g][c0], r1i1 = sR1I[g][c1];
        #pragma unroll
        for (int r = 0; r < 4; ++r) {
          int tj = quad * 4 + r;
          float a0 = q0[r] + r1i0, b0 = q0[r] + sR1J[tj][c0];
          float a1v = q1[r] + r1i1, b1v = q1[r] + sR1J[tj][c1];
          if (diagblk && tj == g) {
            a0 += sDgI[g][c0]; b0 = a0;
            a1v += sDgI[g][c1]; b1v = a1v;
          }
          float hA0 = fmaxf(a0, 0.f), hB0 = fmaxf(b0, 0.f);
          float hA1 = fmaxf(a1v, 0.f), hB1 = fmaxf(b1v, 0.f);
          int pos = g * 16 + tj;
          sPA[pos][c0] = (__bf16)(hA0 + hB0);  sV[pos][c0] = (__bf16)(hA0 - hB0);
          sPA[pos][c1] = (__bf16)(hA1 + hB1);  sV[pos][c1] = (__bf16)(hA1 - hB1);
        }
      }
    }
    __syncthreads();

    // ---- layer-2: P = U.Wp, Mm = V.Wm; a1 = P+Mm+bcast_i, a2 = P-Mm+bcast_j
    const int s0 = m, s1 = m + 16;
    bf16x8 wp0 = *(const bf16x8*)&sWp[s0][8 * quad];
    bf16x8 wp1 = *(const bf16x8*)&sWp[s1][8 * quad];
    bf16x8 wm0 = *(const bf16x8*)&sWm[s0][8 * quad];
    bf16x8 wm1 = *(const bf16x8*)&sWm[s1][8 * quad];
    float ct0 = sCT2[s0], ct1 = sCT2[s1];
    float acc0 = 0.f, acc1 = 0.f;
    #pragma unroll
    for (int gg = 0; gg < 4; ++gg) {
      int g = wv * 4 + gg;
      bf16x8 ua = *(const bf16x8*)&sPA[g * 16 + m][8 * quad];
      bf16x8 va = *(const bf16x8*)&sV [g * 16 + m][8 * quad];
      f32x4 P0 = MFMA(ua, wp0, zero);
      f32x4 M0 = MFMA(va, wm0, zero);
      f32x4 P1 = MFMA(ua, wp1, zero);
      f32x4 M1 = MFMA(va, wm1, zero);
      float crI0 = sCR2I[g][s0], crI1 = sCR2I[g][s1];
      float cd0 = sCD2I[g][s0],  cd1 = sCD2I[g][s1];
      #pragma unroll
      for (int r = 0; r < 4; ++r) {
        int tj = quad * 4 + r;
        float a1 = P0[r] + M0[r] + crI0 + ct0;
        float a2 = P0[r] - M0[r] + sCR2J[tj][s0] + ct0;
        float b1v = P1[r] + M1[r] + crI1 + ct1;
        float b2v = P1[r] - M1[r] + sCR2J[tj][s1] + ct1;
        if (diagblk && tj == g) { a1 += cd0; b1v += cd1; }
        acc0 += fmaxf(a1, 0.f); acc1 += fmaxf(b1v, 0.f);
        if (mirror) { acc0 += fmaxf(a2, 0.f); acc1 += fmaxf(b2v, 0.f); }
      }
    }
    acc0 += __shfl_down(acc0, 32, 64); acc0 += __shfl_down(acc0, 16, 64);
    acc1 += __shfl_down(acc1, 32, 64); acc1 += __shfl_down(acc1, 16, 64);
    if (ln < 16) { red[wv][ln] = acc0; red[wv][ln + 16] = acc1; }
    __syncthreads();
    if (t < NC) {
      float v = red[0][t] + red[1][t] + red[2][t] + red[3][t];
      atomicAdd(&G[b * NC + t], v);
    }
}

// ---------------- k5: decoder MLP 32->128->128->1 ---------------------------
__global__ __launch_bounds__(128) void k5_mlp(
    const float* __restrict__ G, const float* __restrict__ D1, const float* __restrict__ db1,
    const float* __restrict__ D2, const float* __restrict__ db2,
    const float* __restrict__ D3, const float* __restrict__ db3,
    float* __restrict__ out)
{
    int b = blockIdx.x, t = threadIdx.x;
    __shared__ float a[NC], h2s[128], r2[2];
    if (t < NC) a[t] = fmaxf(G[b * NC + t], 0.f);
    __syncthreads();
    float acc = db1[t];
    #pragma unroll
    for (int s = 0; s < NC; ++s) acc += a[s] * D1[s * 128 + t];
    float h2 = fmaxf(acc, 0.f);
    h2s[t] = h2;
    __syncthreads();
    float acc2 = db2[t];
    for (int u = 0; u < 128; ++u) acc2 += h2s[u] * D2[u * 128 + t];
    float h3 = fmaxf(acc2, 0.f);
    float v = h3 * D3[t];
    #pragma unroll
    for (int off = 32; off > 0; off >>= 1) v += __shfl_down(v, off, 64);
    if ((t & 63) == 0) r2[t >> 6] = v;
    __syncthreads();
    if (t == 0) out[b] = r2[0] + r2[1] + db3[0];
}

extern "C" void kernel_launch(void* const* d_in, const int* in_sizes, int n_in,
                              void* d_out, int out_size, void* d_ws, size_t ws_size,
                              hipStream_t stream)
{
    const float* x   = (const float*)d_in[0];
    const float* W1  = (const float*)d_in[1];
    const float* b1  = (const float*)d_in[2];
    const float* W2  = (const float*)d_in[3];
    const float* b2  = (const float*)d_in[4];
    const float* D1  = (const float*)d_in[5];
    const float* db1 = (const float*)d_in[6];
    const float* D2  = (const float*)d_in[7];
    const float* db2 = (const float*)d_in[8];
    const float* D3  = (const float*)d_in[9];
    const float* db3 = (const float*)d_in[10];
    float* out = (float*)d_out;

    float* w = (float*)d_ws;
    float* pS    = w; w += NB * ND;        // 128
    float* pT1   = w; w += NB * NC;        // 256
    float* pTot1 = w; w += NB * NC;
    float* pG    = w; w += NB * NC;
    float* pR1   = w; w += NB * NN * NC;   // 65536
    float* pDg1  = w; w += NB * NN * NC;
    float* pCD2  = w; w += NB * NN * NC;
    float* pCR2  = w; w += NB * NN * NC;
    float* pW2d  = w; w += NC * NC;
    float* pW2r  = w; w += NC * NC;
    float* pW2t  = w; w += NC * NC;
    __bf16* bw = (__bf16*)w;
    __bf16* pA1wT = bw; bw += NC * ND;     // 512
    __bf16* pWpT  = bw; bw += NC * NC;     // 1024
    __bf16* pWmT  = bw; bw += NC * NC;

    hipLaunchKernelGGL(kB_pre, dim3(NB), dim3(256), 0, stream,
                       x, W1, b1, W2, pS, pT1, pTot1, pG,
                       pW2d, pW2r, pW2t, pA1wT, pWpT, pWmT);
    hipLaunchKernelGGL(kC_rows, dim3(NN, NB), dim3(256), 0, stream,
                       x, W1, pS, pT1, pA1wT, pW2d, pW2r,
                       pR1, pDg1, pTot1, pCD2, pCR2);
    hipLaunchKernelGGL(kD_main, dim3(136, NB), dim3(256), 0, stream,
                       x, pR1, pDg1, pT1, pCD2, pCR2, pTot1, pW2t, b2,
                       pA1wT, pWpT, pWmT, pG);
    hipLaunchKernelGGL(k5_mlp, dim3(NB), dim3(128), 0, stream,
                       pG, D1, db1, D2, db2, D3, db3, out);
}

// Round 4
// 119.247 us; speedup vs baseline: 2.5030x; 1.0332x over previous
//
#include <hip/hip_runtime.h>
#include <hip/hip_bf16.h>

// MiniEq2Net round 4. B=8, n=256, nin=16, C=32, DH=128.
//
//   h1[c,i,j] = relu( Q[c,i,j] + R1[c,i] + T1[c] + (i==j)*Dg1[c,i] )
//     Q = p[pos x 16d] . A1w[16d x 32c],  p_d = x[i,d]*x[j,d]   (symmetric)
//   out2(i,j)[s] = sum_c hA[c]*W0[c,s] + hB[c]*W1[c,s] + bcast   (u/v trick)
//   g[b,s] = sum_ij relu(out2); then MLP 32->128->128->1.
//
// Round-4 changes vs round 3:
//  - kB eliminated: every block builds its weight fragments from raw L2-hot
//    W1/W2 (fully parallel) instead of serializing on an 8-block pre-kernel.
//  - kC tiled: 8 rows/block (grid 32x8=256 = 1 block/CU), x-slab staged once
//    per 8 rows (16x less staging), padded LDS strides (17-f32 / 40-48 bf16)
//    for conflict-free access, register row-sum accumulation across j-strips.
//  - Atomics + zero-init replaced by partial-sum buffers (TotP from kC,
//    GP from kD, reduced in kD/k5) -> no memset launch needed.

#define NB 8
#define NN 256
#define ND 16
#define NC 32
#define W1S 160   // W1 row stride (floats): [2*ND][NC][5]
#define W2S 160   // W2 row stride (floats): [NC][NC][5]

using bf16x8 = __attribute__((ext_vector_type(8))) __bf16;
using f32x4  = __attribute__((ext_vector_type(4))) float;

#define MFMA(a, b, c) __builtin_amdgcn_mfma_f32_16x16x32_bf16((a), (b), (c), 0, 0, 0)

// ---------------- kC: 8-row tiles; layer-1 row/diag/total sums + CD2/CR2 ----
// grid (NN/8=32, NB), 256 threads.
__global__ __launch_bounds__(256) void kC_rows(
    const float* __restrict__ x, const float* __restrict__ W1,
    const float* __restrict__ b1, const float* __restrict__ W2,
    float* __restrict__ T1g, float* __restrict__ R1, float* __restrict__ Dg1,
    float* __restrict__ TotP, float* __restrict__ CD2, float* __restrict__ CR2)
{
    const int TI = blockIdx.x, b = blockIdx.y, t = threadIdx.x;
    __shared__ __align__(16) float  sX[NN][ND + 1];   // 17408 B, stride 17 (odd->conflict-free)
    __shared__ __align__(16) __bf16 sP[NN][40];       // 20480 B, stride 40 (2-way=free)
    __shared__ __align__(16) __bf16 sBQ[NC][48];      // 3072 B
    __shared__ float part[16][ND + 1];
    __shared__ float sS[ND], sT1[NC];
    __shared__ float sRT[8][NC], sDgL[8][NC], sRow[8][NC], sDiag[8][NC];

    const float* xg = x + b * NN * ND;
    #pragma unroll
    for (int kk = 0; kk < 16; ++kk) {
        int idx = t + kk * 256;
        sX[idx >> 4][idx & 15] = xg[idx];
    }
    // A1w B-table from raw W1 (k<16 data, 16..47 zero)
    #pragma unroll
    for (int kk = 0; kk < 2; ++kk) {
        int idx = t + kk * 256;
        int c = idx >> 4, k = idx & 15;
        sBQ[c][k] = (__bf16)(W1[(ND + k) * W1S + c * 5 + 0]
                           + W1[(ND + k) * W1S + c * 5 + 1]);
    }
    #pragma unroll
    for (int kk = 0; kk < 4; ++kk) {
        int idx = t + kk * 256;
        sBQ[idx >> 5][16 + (idx & 31)] = (__bf16)0.f;
    }
    // pre-zero sP k=16..31 (dwords r*20+8..15)
    {
        uint32_t* z = (uint32_t*)&sP[0][0];
        #pragma unroll
        for (int kk = 0; kk < 8; ++kk) {
            int idx = t + kk * 256;
            z[(idx >> 3) * 20 + 8 + (idx & 7)] = 0u;
        }
    }
    __syncthreads();

    // column sums S[d]
    {
        int rr = t >> 4, d = t & 15;
        float p = 0.f;
        #pragma unroll
        for (int k = 0; k < 16; ++k) p += sX[rr + (k << 4)][d];
        part[rr][d] = p;
    }
    __syncthreads();
    if (t < ND) {
        float s = 0.f;
        #pragma unroll
        for (int k = 0; k < 16; ++k) s += part[k][t];
        sS[t] = s;
    }
    __syncthreads();
    if (t < NC) {   // T1
        int c = t; float tt = 0.f;
        #pragma unroll
        for (int d = 0; d < ND; ++d)
            tt += sS[d] * W1[d * W1S + c * 5 + 4]
                + sS[d] * sS[d] * W1[(ND + d) * W1S + c * 5 + 4];
        float v = tt * (1.f / 65536.f) + b1[c];
        sT1[c] = v;
        if (TI == 0) T1g[b * NC + c] = v;
    }
    __syncthreads();
    // R1/Dg1 for the 8 tile rows (one (i_l,c) item per thread)
    {
        int i_l = t >> 5, c = t & 31;
        int gi = TI * 8 + i_l;
        float r = 0.f, dg = 0.f;
        #pragma unroll
        for (int d = 0; d < ND; ++d) {
            float xi = sX[gi][d];
            const float* wa = W1 + d * W1S + c * 5;
            const float* wb = W1 + (ND + d) * W1S + c * 5;
            r  += xi * wa[3] + xi * sS[d] * wb[3];
            dg += xi * (wa[0] + wa[1] + wa[2]) + xi * xi * wb[2];
        }
        r *= (1.f / 256.f);
        R1[(b * NN + gi) * NC + c] = r;
        Dg1[(b * NN + gi) * NC + c] = dg;
        sRT[i_l][c] = sT1[c] + r;   // folded epilogue constant
        sDgL[i_l][c] = dg;
    }

    const int ln = t & 63, wv = t >> 6;
    const int m = ln & 15, quad = ln >> 4;
    bf16x8 bq0 = *(const bf16x8*)&sBQ[m][8 * quad];
    bf16x8 bq1 = *(const bf16x8*)&sBQ[m + 16][8 * quad];
    f32x4 zero = {0.f, 0.f, 0.f, 0.f};
    float rs0[4] = {0.f, 0.f, 0.f, 0.f}, rs1[4] = {0.f, 0.f, 0.f, 0.f};
    const int i_base = TI * 8;

    // 8 j-strips of 32: positions pos = i_l*32 + j_l (256/strip)
    for (int jg = 0; jg < 8; ++jg) {
        __syncthreads();   // protect sP from previous strip's readers
        {
            int i_l = t >> 5, j_l = t & 31;
            const float* xi = &sX[i_base + i_l][0];
            const float* xj = &sX[jg * 32 + j_l][0];
            bf16x8 v0, v1;
            #pragma unroll
            for (int d = 0; d < 8; ++d) v0[d] = (__bf16)(xi[d] * xj[d]);
            #pragma unroll
            for (int d = 0; d < 8; ++d) v1[d] = (__bf16)(xi[8 + d] * xj[8 + d]);
            *(bf16x8*)&sP[t][0] = v0;
            *(bf16x8*)&sP[t][8] = v1;
        }
        __syncthreads();
        #pragma unroll
        for (int gg = 0; gg < 4; ++gg) {
            int g = wv * 4 + gg;
            bf16x8 av = *(const bf16x8*)&sP[g * 16 + m][8 * quad];
            f32x4 q0 = MFMA(av, bq0, zero);
            f32x4 q1 = MFMA(av, bq1, zero);
            int i_l = g >> 1;
            int gi = i_base + i_l;
            float rt0 = sRT[i_l][m], rt1 = sRT[i_l][m + 16];
            int jb = jg * 32 + (g & 1) * 16 + quad * 4;
            #pragma unroll
            for (int r = 0; r < 4; ++r) {
                float v0 = q0[r] + rt0, v1 = q1[r] + rt1;
                bool dgf = (jb + r == gi);
                if (dgf) { v0 += sDgL[i_l][m]; v1 += sDgL[i_l][m + 16]; }
                float h0 = fmaxf(v0, 0.f), h1 = fmaxf(v1, 0.f);
                if (dgf) { sDiag[i_l][m] = h0; sDiag[i_l][m + 16] = h1; }
                rs0[gg] += h0; rs1[gg] += h1;
            }
        }
    }
    // reduce row sums: gg pairs share i_l = wv*2 + (gg>>1)
    float a0 = rs0[0] + rs0[1], a1 = rs0[2] + rs0[3];
    float b0 = rs1[0] + rs1[1], b1v = rs1[2] + rs1[3];
    a0 += __shfl_down(a0, 32, 64);  a0 += __shfl_down(a0, 16, 64);
    a1 += __shfl_down(a1, 32, 64);  a1 += __shfl_down(a1, 16, 64);
    b0 += __shfl_down(b0, 32, 64);  b0 += __shfl_down(b0, 16, 64);
    b1v += __shfl_down(b1v, 32, 64); b1v += __shfl_down(b1v, 16, 64);
    __syncthreads();
    if (ln < 16) {
        sRow[wv * 2][ln] = a0;       sRow[wv * 2 + 1][ln] = a1;
        sRow[wv * 2][ln + 16] = b0;  sRow[wv * 2 + 1][ln + 16] = b1v;
    }
    __syncthreads();
    if (t < NC) {   // per-block Tot partial (no atomics, no zero-init needed)
        float s = 0.f;
        #pragma unroll
        for (int i = 0; i < 8; ++i) s += sRow[i][t];
        TotP[TI * (NB * NC) + b * NC + t] = s;
    }
    {   // CD2/CR2 for the 8 rows (raw W2, L2-hot)
        int i_l = t >> 5, s = t & 31;
        int gi = i_base + i_l;
        float cd = 0.f, cr = 0.f;
        #pragma unroll
        for (int c = 0; c < NC; ++c) {
            cd += sDiag[i_l][c] * W2[c * W2S + s * 5 + 2];
            cr += sRow[i_l][c]  * W2[c * W2S + s * 5 + 3];
        }
        CD2[(b * NN + gi) * NC + s] = cd;
        CR2[(b * NN + gi) * NC + s] = cr * (1.f / 256.f);
    }
}

// ---------------- kD: tile-pair fused layer1+layer2+reduce (MFMA) -----------
__global__ __launch_bounds__(256) void kD_main(
    const float* __restrict__ x, const float* __restrict__ W1,
    const float* __restrict__ W2, const float* __restrict__ b2,
    const float* __restrict__ T1g, const float* __restrict__ R1g,
    const float* __restrict__ Dg1g, const float* __restrict__ CD2g,
    const float* __restrict__ CR2g, const float* __restrict__ TotP,
    float* __restrict__ GP)
{
    const int b = blockIdx.y, t = threadIdx.x;
    int TI = 0, rem = blockIdx.x;
    while (rem >= 16 - TI) { rem -= 16 - TI; ++TI; }
    const int TJ = TI + rem;
    const bool diagblk = (TI == TJ), mirror = !diagblk;

    __shared__ __align__(16) __bf16 sPA[NN][40];   // p, then overwritten by U
    __shared__ __align__(16) __bf16 sV[NN][40];
    __shared__ __align__(16) __bf16 sBQ[NC][48];
    __shared__ __align__(16) __bf16 sWp[NC][40];
    __shared__ __align__(16) __bf16 sWm[NC][40];
    __shared__ float sXI[16][ND + 1], sXJ[16][ND + 1];
    __shared__ float sR1I[16][NC], sR1J[16][NC];
    __shared__ float sCR2I[16][NC], sCR2J[16][NC];
    __shared__ float sCD2I[16][NC], sDgI[16][NC];
    __shared__ float sT1[NC], sTot[NC], sCT2[NC];
    __shared__ float red[4][NC];

    { int r = t >> 4, d = t & 15;
      sXI[r][d] = x[(b * NN + TI * 16 + r) * ND + d];
      sXJ[r][d] = x[(b * NN + TJ * 16 + r) * ND + d]; }
    #pragma unroll
    for (int kk = 0; kk < 2; ++kk) {
      int idx = t + kk * 256; int r = idx >> 5, c = idx & 31;
      sR1I[r][c]  = R1g [(b * NN + TI * 16 + r) * NC + c];
      sR1J[r][c]  = R1g [(b * NN + TJ * 16 + r) * NC + c];
      sCR2I[r][c] = CR2g[(b * NN + TI * 16 + r) * NC + c];
      sCR2J[r][c] = CR2g[(b * NN + TJ * 16 + r) * NC + c];
      sCD2I[r][c] = CD2g[(b * NN + TI * 16 + r) * NC + c];
      sDgI[r][c]  = Dg1g[(b * NN + TI * 16 + r) * NC + c];
    }
    #pragma unroll
    for (int kk = 0; kk < 2; ++kk) {   // A1w table from raw W1
      int idx = t + kk * 256; int c = idx >> 4, k = idx & 15;
      sBQ[c][k] = (__bf16)(W1[(ND + k) * W1S + c * 5 + 0]
                         + W1[(ND + k) * W1S + c * 5 + 1]);
    }
    #pragma unroll
    for (int kk = 0; kk < 4; ++kk) {
      int idx = t + kk * 256;
      sBQ[idx >> 5][16 + (idx & 31)] = (__bf16)0.f;
    }
    #pragma unroll
    for (int kk = 0; kk < 4; ++kk) {   // Wp/Wm from raw W2
      int idx = t + kk * 256; int s = idx >> 5, c = idx & 31;
      float w0 = W2[c * W2S + s * 5 + 0], w1 = W2[c * W2S + s * 5 + 1];
      sWp[s][c] = (__bf16)((w0 + w1) * 0.5f);
      sWm[s][c] = (__bf16)((w0 - w1) * 0.5f);
    }
    if (t < NC) {
      sT1[t] = T1g[b * NC + t];
      float tot = 0.f;
      #pragma unroll
      for (int k = 0; k < 32; ++k) tot += TotP[k * (NB * NC) + b * NC + t];
      sTot[t] = tot;
    }
    __syncthreads();

    {   // p row for position (ti,tj) = (t>>4, t&15); zeros in k=16..31
      int ti = t >> 4, tj = t & 15;
      bf16x8 v0, v1, zv;
      #pragma unroll
      for (int d = 0; d < 8; ++d) {
        v0[d] = (__bf16)(sXI[ti][d] * sXJ[tj][d]);
        v1[d] = (__bf16)(sXI[ti][8 + d] * sXJ[tj][8 + d]);
        zv[d] = (__bf16)0.f;
      }
      *(bf16x8*)&sPA[t][0]  = v0;
      *(bf16x8*)&sPA[t][8]  = v1;
      *(bf16x8*)&sPA[t][16] = zv;
      *(bf16x8*)&sPA[t][24] = zv;
    }
    if (t < NC) {   // CT2 from sTot
      float ct = 0.f;
      #pragma unroll
      for (int c = 0; c < NC; ++c) ct += sTot[c] * W2[c * W2S + t * 5 + 4];
      sCT2[t] = ct * (1.f / 65536.f) + b2[t];
    }
    __syncthreads();

    const int wv = t >> 6, ln = t & 63;
    const int m = ln & 15, quad = ln >> 4;
    const int c0 = m, c1 = m + 16;
    f32x4 zero = {0.f, 0.f, 0.f, 0.f};

    // ---- layer-1: h = relu(Q + T1 + R1); build u,v (U overwrites sPA) ----
    // Each wave reads/writes only rows wv*64..wv*64+63; within a gg the
    // ds_read precedes the writes in wave program order -> in-place is safe.
    {
      bf16x8 bq0 = *(const bf16x8*)&sBQ[c0][8 * quad];
      bf16x8 bq1 = *(const bf16x8*)&sBQ[c1][8 * quad];
      float t10 = sT1[c0], t11 = sT1[c1];
      #pragma unroll
      for (int gg = 0; gg < 4; ++gg) {
        int g = wv * 4 + gg;
        bf16x8 av = *(const bf16x8*)&sPA[g * 16 + m][8 * quad];
        f32x4 q0 = MFMA(av, bq0, zero);
        f32x4 q1 = MFMA(av, bq1, zero);
        float r1i0 = sR1I[g][c0] + t10, r1i1 = sR1I[g][c1] + t11;
        #pragma unroll
        for (int r = 0; r < 4; ++r) {
          int tj = quad * 4 + r;
          float a0 = q0[r] + r1i0, b0 = q0[r] + sR1J[tj][c0] + t10;
          float a1v = q1[r] + r1i1, b1v = q1[r] + sR1J[tj][c1] + t11;
          if (diagblk && tj == g) {
            a0 += sDgI[g][c0]; b0 = a0;
            a1v += sDgI[g][c1]; b1v = a1v;
          }
          float hA0 = fmaxf(a0, 0.f), hB0 = fmaxf(b0, 0.f);
          float hA1 = fmaxf(a1v, 0.f), hB1 = fmaxf(b1v, 0.f);
          int pos = g * 16 + tj;
          sPA[pos][c0] = (__bf16)(hA0 + hB0);  sV[pos][c0] = (__bf16)(hA0 - hB0);
          sPA[pos][c1] = (__bf16)(hA1 + hB1);  sV[pos][c1] = (__bf16)(hA1 - hB1);
        }
      }
    }
    __syncthreads();

    // ---- layer-2: a1 = U.Wp + V.Wm + bcast_i, a2 = U.Wp - V.Wm + bcast_j
    const int s0 = m, s1 = m + 16;
    bf16x8 wp0 = *(const bf16x8*)&sWp[s0][8 * quad];
    bf16x8 wp1 = *(const bf16x8*)&sWp[s1][8 * quad];
    bf16x8 wm0 = *(const bf16x8*)&sWm[s0][8 * quad];
    bf16x8 wm1 = *(const bf16x8*)&sWm[s1][8 * quad];
    float ct0 = sCT2[s0], ct1 = sCT2[s1];
    float acc0 = 0.f, acc1 = 0.f;
    #pragma unroll
    for (int gg = 0; gg < 4; ++gg) {
      int g = wv * 4 + gg;
      bf16x8 ua = *(const bf16x8*)&sPA[g * 16 + m][8 * quad];
      bf16x8 va = *(const bf16x8*)&sV [g * 16 + m][8 * quad];
      f32x4 P0 = MFMA(ua, wp0, zero);
      f32x4 M0 = MFMA(va, wm0, zero);
      f32x4 P1 = MFMA(ua, wp1, zero);
      f32x4 M1 = MFMA(va, wm1, zero);
      float crI0 = sCR2I[g][s0] + ct0, crI1 = sCR2I[g][s1] + ct1;
      float cd0 = sCD2I[g][s0], cd1 = sCD2I[g][s1];
      #pragma unroll
      for (int r = 0; r < 4; ++r) {
        int tj = quad * 4 + r;
        float a1 = P0[r] + M0[r] + crI0;
        float a2 = P0[r] - M0[r] + sCR2J[tj][s0] + ct0;
        float e1 = P1[r] + M1[r] + crI1;
        float e2 = P1[r] - M1[r] + sCR2J[tj][s1] + ct1;
        if (diagblk && tj == g) { a1 += cd0; e1 += cd1; }
        acc0 += fmaxf(a1, 0.f); acc1 += fmaxf(e1, 0.f);
        if (mirror) { acc0 += fmaxf(a2, 0.f); acc1 += fmaxf(e2, 0.f); }
      }
    }
    acc0 += __shfl_down(acc0, 32, 64); acc0 += __shfl_down(acc0, 16, 64);
    acc1 += __shfl_down(acc1, 32, 64); acc1 += __shfl_down(acc1, 16, 64);
    if (ln < 16) { red[wv][ln] = acc0; red[wv][ln + 16] = acc1; }
    __syncthreads();
    if (t < NC) {   // per-block partial (no atomics, no zero-init)
      GP[blockIdx.x * (NB * NC) + b * NC + t]
          = red[0][t] + red[1][t] + red[2][t] + red[3][t];
    }
}

// ---------------- k5: reduce GP (136 partials) + MLP 32->128->128->1 --------
__global__ __launch_bounds__(128) void k5_mlp(
    const float* __restrict__ GP, const float* __restrict__ D1,
    const float* __restrict__ db1, const float* __restrict__ D2,
    const float* __restrict__ db2, const float* __restrict__ D3,
    const float* __restrict__ db3, float* __restrict__ out)
{
    int b = blockIdx.x, t = threadIdx.x;
    __shared__ float sGp[4][NC], a[NC], h2s[128], r2[2];
    {
        int q = t >> 5, s = t & 31;
        float p = 0.f;
        for (int k = q; k < 136; k += 4) p += GP[k * (NB * NC) + b * NC + s];
        sGp[q][s] = p;
    }
    __syncthreads();
    if (t < NC) a[t] = fmaxf(sGp[0][t] + sGp[1][t] + sGp[2][t] + sGp[3][t], 0.f);
    __syncthreads();
    float acc = db1[t];
    #pragma unroll
    for (int s = 0; s < NC; ++s) acc += a[s] * D1[s * 128 + t];
    float h2 = fmaxf(acc, 0.f);
    h2s[t] = h2;
    __syncthreads();
    float acc2 = db2[t];
    for (int u = 0; u < 128; ++u) acc2 += h2s[u] * D2[u * 128 + t];
    float h3 = fmaxf(acc2, 0.f);
    float v = h3 * D3[t];
    #pragma unroll
    for (int off = 32; off > 0; off >>= 1) v += __shfl_down(v, off, 64);
    if ((t & 63) == 0) r2[t >> 6] = v;
    __syncthreads();
    if (t == 0) out[b] = r2[0] + r2[1] + db3[0];
}

extern "C" void kernel_launch(void* const* d_in, const int* in_sizes, int n_in,
                              void* d_out, int out_size, void* d_ws, size_t ws_size,
                              hipStream_t stream)
{
    const float* x   = (const float*)d_in[0];
    const float* W1  = (const float*)d_in[1];
    const float* b1  = (const float*)d_in[2];
    const float* W2  = (const float*)d_in[3];
    const float* b2  = (const float*)d_in[4];
    const float* D1  = (const float*)d_in[5];
    const float* db1 = (const float*)d_in[6];
    const float* D2  = (const float*)d_in[7];
    const float* db2 = (const float*)d_in[8];
    const float* D3  = (const float*)d_in[9];
    const float* db3 = (const float*)d_in[10];
    float* out = (float*)d_out;

    float* w = (float*)d_ws;
    float* pT1   = w; w += NB * NC;          // 256
    float* pTotP = w; w += 32 * NB * NC;     // 8192
    float* pGP   = w; w += 136 * NB * NC;    // 34816
    float* pR1   = w; w += NB * NN * NC;     // 65536
    float* pDg1  = w; w += NB * NN * NC;
    float* pCD2  = w; w += NB * NN * NC;
    float* pCR2  = w; w += NB * NN * NC;

    hipLaunchKernelGGL(kC_rows, dim3(32, NB), dim3(256), 0, stream,
                       x, W1, b1, W2, pT1, pR1, pDg1, pTotP, pCD2, pCR2);
    hipLaunchKernelGGL(kD_main, dim3(136, NB), dim3(256), 0, stream,
                       x, W1, W2, b2, pT1, pR1, pDg1, pCD2, pCR2, pTotP, pGP);
    hipLaunchKernelGGL(k5_mlp, dim3(NB), dim3(128), 0, stream,
                       pGP, D1, db1, D2, db2, D3, db3, out);
}